// Round 8
// baseline (346.178 us; speedup 1.0000x reference)
//
#include <hip/hip_runtime.h>
#include <stdint.h>

// positional_spiking_attention — v8: barrier-free streaming i8 GEMM (no LDS).
// Spikes in {0,1} as u8 (exact). Weights w = s1*a1 + s2*a2 (i8 planes);
// i32 MFMA accumulation exact -> results bitwise = v7. Near-threshold columns
// (|m-0.5| < 1e-3) compacted + recomputed with bit-exact serial fp32 chain.
// Row layout: r = bi*4 + t; lane's 4 accum regs = T=4 steps of one column.
//
// GEMM: W pre-arranged in fragment order [mat][colblk][plane][m][col][16B]
// (m = k-16B-chunk). Block = 256 rows x 64 cols, wave = 64 rows; ks-loop with
// register double-buffer, 32 MFMA : 12 global loads per ks, ZERO barriers.
// blockIdx.x = colblk -> XCD pinning (linear%8) keeps W L2-resident per XCD.
//
// Workspace:
//   0    xsb  u8 first-LIF spikes [bi*4+t][512] (8MB)
//   8M   qs / 16M ks / 24M vs / 32M sA  (u8, same layout)
//   40M  Wq   4 mats x [8 colblk][2 pl][32 m][64 c][16B] (2MB)
//   44M  scl  [mat][2][512] f32 scales
//   48M  list u32 flagged ids (cap 5M) ; 70M cnt

#define T_ 4
#define B_ 4
#define L_ 1024
#define D_ 512
#define BI_ (B_*L_)                 // 4096 (b,l) columns
#define STRIDE4 (B_*L_*D_/4)        // 524288 4-elem groups per t-slice
#define INV_STD 0.9999950000374997f
#define EPS_FLAG 1e-3f
#define LIST_CAP 5000000u

typedef unsigned int   u32;
typedef unsigned char  u8;
typedef int i32x4 __attribute__((ext_vector_type(4)));

static __device__ __forceinline__ float spike_of(float m) {
  return m > 0.5f ? 1.0f : 0.0f;
}

// ------ weight quantize into fragment-ordered image -------------------------
__global__ __launch_bounds__(256) void k_wsplit(const float* __restrict__ qw,
    const float* __restrict__ kw, const float* __restrict__ vw,
    const float* __restrict__ lw, u8* __restrict__ Wq,
    float* __restrict__ scl, u32* __restrict__ cnt) {
  if (blockIdx.x == 0 && threadIdx.x == 0) *cnt = 0;
  int gid = blockIdx.x * 4 + (threadIdx.x >> 6);   // wave id 0..2047
  int mat = gid >> 9, e = gid & 511;
  int lane = threadIdx.x & 63;
  const float* W = mat == 0 ? qw : mat == 1 ? kw : mat == 2 ? vw : lw;
  const float4* w4 = (const float4*)(W + (size_t)e * 512 + lane * 8);
  float4 wa = w4[0], wb = w4[1];
  float w[8] = {wa.x, wa.y, wa.z, wa.w, wb.x, wb.y, wb.z, wb.w};
  float am = 0.f;
#pragma unroll
  for (int j = 0; j < 8; ++j) am = fmaxf(am, fabsf(w[j]));
#pragma unroll
  for (int off = 1; off < 64; off <<= 1)
    am = fmaxf(am, __shfl_xor(am, off, 64));
  float s1 = am > 0.f ? am * (1.0f / 127.0f) : 1.0f;
  float s2 = s1 * (1.0f / 254.0f);
  float inv1 = 1.0f / s1, inv2 = 1.0f / s2;
  u32 p1lo = 0, p1hi = 0, p2lo = 0, p2hi = 0;
#pragma unroll
  for (int j = 0; j < 8; ++j) {
    float q1 = rintf(w[j] * inv1);
    q1 = fminf(127.f, fmaxf(-127.f, q1));
    float r = w[j] - s1 * q1;
    float q2 = rintf(r * inv2);
    q2 = fminf(127.f, fmaxf(-127.f, q2));
    u32 b1 = (u32)(u8)(signed char)(int)q1;
    u32 b2 = (u32)(u8)(signed char)(int)q2;
    if (j < 4) { p1lo |= b1 << (j * 8); p2lo |= b2 << (j * 8); }
    else       { p1hi |= b1 << ((j - 4) * 8); p2hi |= b2 << ((j - 4) * 8); }
  }
  // fragment-order image: [colblk][plane][m=j>>4][c=e&63][16B]
  u8* base = Wq + (size_t)mat * 524288 + (size_t)(e >> 6) * 65536 +
             (size_t)(lane >> 1) * 1024 + (size_t)(e & 63) * 16 + (lane & 1) * 8;
  *(uint2*)base             = make_uint2(p1lo, p1hi);   // plane 0
  *(uint2*)(base + 32768)   = make_uint2(p2lo, p2hi);   // plane 1
  if (lane == 0) {
    scl[mat * 1024 + e] = s1;
    scl[mat * 1024 + 512 + e] = s2;
  }
}

// ---------------- first LIF: x[t][bi][d] -> xsb[bi*4+t][d] (u8) -------------
__global__ __launch_bounds__(256) void k_lif_first(const float* __restrict__ x,
                                                   u8* __restrict__ xsb) {
  int idx = blockIdx.x * 256 + threadIdx.x;       // bi*128 + d4
  if (idx >= STRIDE4) return;
  const int bi = idx >> 7, d4 = idx & 127;
  const float4* x4 = (const float4*)x;
  uchar4* o4 = (uchar4*)xsb;
  float m[4], s[4];
  float4 v = x4[idx];
  m[0] = v.x; m[1] = v.y; m[2] = v.z; m[3] = v.w;
#pragma unroll
  for (int c = 0; c < 4; ++c) s[c] = spike_of(m[c]);
  o4[(bi * 4 + 0) * 128 + d4] =
      make_uchar4((u8)s[0], (u8)s[1], (u8)s[2], (u8)s[3]);
#pragma unroll
  for (int t = 1; t < T_; ++t) {
    v = x4[idx + t * STRIDE4];
    float xv[4] = {v.x, v.y, v.z, v.w};
#pragma unroll
    for (int c = 0; c < 4; ++c) {
      m[c] = m[c] * 0.25f * (1.0f - s[c]) + xv[c];
      s[c] = spike_of(m[c]);
    }
    o4[(bi * 4 + t) * 128 + d4] =
        make_uchar4((u8)s[0], (u8)s[1], (u8)s[2], (u8)s[3]);
  }
}

// ======= barrier-free streaming i8 GEMM core ================================
// Wave: 64 rows (4 strips of 16) x 64 cols. acc[strip][cf][plane].
__device__ __forceinline__ void gemm_flat(const u8* __restrict__ Ab,
    const u8* __restrict__ Wc, int rowbase, int la, int lg,
    i32x4 (&acc)[4][4][2]) {
  const u8* ap = Ab + (size_t)(rowbase + la) * 512 + lg * 16;
  const u8* bp = Wc + lg * 1024 + la * 16;

#pragma unroll
  for (int s = 0; s < 4; ++s)
#pragma unroll
    for (int cf = 0; cf < 4; ++cf)
#pragma unroll
      for (int pl = 0; pl < 2; ++pl) acc[s][cf][pl] = (i32x4){0, 0, 0, 0};

  uint4 Abuf[2][4], Bbuf[2][8];
#pragma unroll
  for (int s = 0; s < 4; ++s)
    Abuf[0][s] = *(const uint4*)(ap + s * 8192);
#pragma unroll
  for (int cf = 0; cf < 4; ++cf)
#pragma unroll
    for (int pl = 0; pl < 2; ++pl)
      Bbuf[0][cf * 2 + pl] = *(const uint4*)(bp + pl * 32768 + cf * 256);

#pragma unroll
  for (int ks = 0; ks < 8; ++ks) {
    const int cur = ks & 1, nxt = cur ^ 1;
    if (ks < 7) {
#pragma unroll
      for (int s = 0; s < 4; ++s)
        Abuf[nxt][s] = *(const uint4*)(ap + s * 8192 + (ks + 1) * 64);
#pragma unroll
      for (int cf = 0; cf < 4; ++cf)
#pragma unroll
        for (int pl = 0; pl < 2; ++pl)
          Bbuf[nxt][cf * 2 + pl] =
              *(const uint4*)(bp + (ks + 1) * 4096 + pl * 32768 + cf * 256);
    }
#pragma unroll
    for (int cf = 0; cf < 4; ++cf)
#pragma unroll
      for (int pl = 0; pl < 2; ++pl)
#pragma unroll
        for (int s = 0; s < 4; ++s)
          acc[s][cf][pl] = __builtin_amdgcn_mfma_i32_16x16x64_i8(
              __builtin_bit_cast(i32x4, Abuf[cur][s]),
              __builtin_bit_cast(i32x4, Bbuf[cur][cf * 2 + pl]),
              acc[s][cf][pl], 0, 0, 0);
  }
}

// ------ fused QKV: streaming GEMM + BN + LIF epilogue -----------------------
__global__ __launch_bounds__(256) void k_gemm_qkv(const u8* __restrict__ Ab,
    const u8* __restrict__ Wq, const float* __restrict__ scl,
    const float* __restrict__ qb2, const float* __restrict__ qg,
    const float* __restrict__ qbe,
    const float* __restrict__ kb2, const float* __restrict__ kg,
    const float* __restrict__ kbe,
    const float* __restrict__ vb2, const float* __restrict__ vg,
    const float* __restrict__ vbe,
    u8* __restrict__ qs, u8* __restrict__ ks_, u8* __restrict__ vs,
    u32* __restrict__ list, u32* __restrict__ cnt) {
  const int tid = threadIdx.x;
  const int lane = tid & 63, wid = tid >> 6;
  const int la = lane & 15, lg = lane >> 4;
  const int colblk = blockIdx.x;                  // 0..7 -> XCD pin
  const int tz = blockIdx.z;
  const int rowbase = (blockIdx.y * 4 + wid) * 64;
  const u8* Wc = Wq + (size_t)tz * 524288 + (size_t)colblk * 65536;
  const float* Bb = tz == 0 ? qb2 : tz == 1 ? kb2 : vb2;
  const float* Gg = tz == 0 ? qg  : tz == 1 ? kg  : vg;
  const float* Be = tz == 0 ? qbe : tz == 1 ? kbe : vbe;
  u8* S           = tz == 0 ? qs  : tz == 1 ? ks_ : vs;

  i32x4 acc[4][4][2];
  gemm_flat(Ab, Wc, rowbase, la, lg, acc);

#pragma unroll
  for (int cf = 0; cf < 4; ++cf) {
    int e = colblk * 64 + cf * 16 + la;
    float s1 = scl[tz * 1024 + e];
    float s2 = scl[tz * 1024 + 512 + e];
    float cs = INV_STD * Gg[e];
    float cb = Bb[e], ct = Be[e];
#pragma unroll
    for (int s = 0; s < 4; ++s) {
      int r0 = rowbase + s * 16 + lg * 4;         // bi*4 aligned
      int bi = r0 >> 2;
      float m = 0.f, sp = 0.f;
      int fl = 0;
#pragma unroll
      for (int p = 0; p < 4; ++p) {               // p == t
        float raw = s1 * (float)acc[s][cf][0][p] + s2 * (float)acc[s][cf][1][p];
        float pre = (raw + cb) * cs + ct;
        if (p == 0) m = pre;
        else m = m * 0.25f * (1.0f - sp) + pre;
        sp = spike_of(m);
        if (fabsf(m - 0.5f) < EPS_FLAG) fl = 1;
        S[(size_t)(r0 + p) * 512 + e] = (u8)sp;
      }
      if (fl) {
        u32 pos = atomicAdd(cnt, 1u);
        if (pos < LIST_CAP)
          list[pos] = ((u32)tz << 21) | (u32)(bi * 512 + e);
      }
    }
  }
}

// -------- last GEMM + BN -> fp32 out [t][bi][d] -----------------------------
__global__ __launch_bounds__(256) void k_gemm_out(const u8* __restrict__ Ab,
    const u8* __restrict__ Wq, const float* __restrict__ scl,
    const float* __restrict__ bias, const float* __restrict__ gamma,
    const float* __restrict__ beta, float* __restrict__ Y) {
  const int tid = threadIdx.x;
  const int lane = tid & 63, wid = tid >> 6;
  const int la = lane & 15, lg = lane >> 4;
  const int colblk = blockIdx.x;
  const int rowbase = (blockIdx.y * 4 + wid) * 64;
  const u8* Wc = Wq + 3u * 524288 + (size_t)colblk * 65536;

  i32x4 acc[4][4][2];
  gemm_flat(Ab, Wc, rowbase, la, lg, acc);

#pragma unroll
  for (int cf = 0; cf < 4; ++cf) {
    int e = colblk * 64 + cf * 16 + la;
    float s1 = scl[3 * 1024 + e];
    float s2 = scl[3 * 1024 + 512 + e];
    float cs = INV_STD * gamma[e];
    float cb = bias[e], ct = beta[e];
#pragma unroll
    for (int s = 0; s < 4; ++s) {
      int r0 = rowbase + s * 16 + lg * 4;
      int bi = r0 >> 2;
#pragma unroll
      for (int p = 0; p < 4; ++p) {
        float raw = s1 * (float)acc[s][cf][0][p] + s2 * (float)acc[s][cf][1][p];
        Y[((size_t)p * BI_ + bi) * 512 + e] = (raw + cb) * cs + ct;
      }
    }
  }
}

// ------- fixup: quad-per-item, exact serial fp32 chain, shfl-combine --------
__device__ __forceinline__ void consume32_u8(const float4 (&wb)[8],
                                             const uint4 (&ab)[2], float& c) {
#pragma unroll
  for (int u = 0; u < 8; ++u) {           // u = group of 4 consecutive j
    float4 w = wb[u];
    uint4 t = ab[u >> 2];
    u32 word = (u & 3) == 0 ? t.x : (u & 3) == 1 ? t.y
             : (u & 3) == 2 ? t.z : t.w;
    c += (word & 0xFFu)       ? w.x : 0.0f;   // strict ascending-j order
    c += (word & 0xFF00u)     ? w.y : 0.0f;
    c += (word & 0xFF0000u)   ? w.z : 0.0f;
    c += (word >> 24)         ? w.w : 0.0f;
  }
}

__global__ __launch_bounds__(128) void k_fixup_c(const u8* __restrict__ xsb,
    u8* __restrict__ qs, u8* __restrict__ ks, u8* __restrict__ vs,
    const float* __restrict__ qw, const float* __restrict__ qb2,
    const float* __restrict__ qg, const float* __restrict__ qbe,
    const float* __restrict__ kw, const float* __restrict__ kb2,
    const float* __restrict__ kg, const float* __restrict__ kbe,
    const float* __restrict__ vw, const float* __restrict__ vb2,
    const float* __restrict__ vg, const float* __restrict__ vbe,
    const u32* __restrict__ list, const u32* __restrict__ cnt) {
  u32 n = *cnt;
  if (n > LIST_CAP) n = LIST_CAP;
  u32 tot = n * 4;
  for (u32 ii = blockIdx.x * 128 + threadIdx.x; ii < tot;
       ii += gridDim.x * 128) {
    u32 i = ii >> 2;
    int t = (int)(ii & 3);
    u32 e = list[i];
    int tz = (int)(e >> 21);
    int col = (int)(e & 0x1FFFFFu);
    int bi = col >> 9, d = col & 511;
    const float* W  = tz == 0 ? qw  : tz == 1 ? kw  : vw;
    const float* Bb = tz == 0 ? qb2 : tz == 1 ? kb2 : vb2;
    const float* Gg = tz == 0 ? qg  : tz == 1 ? kg  : vg;
    const float* Be = tz == 0 ? qbe : tz == 1 ? kbe : vbe;
    u8* S           = tz == 0 ? qs  : tz == 1 ? ks  : vs;
    const float4* w4 = (const float4*)(W + (size_t)d * 512);            // 128
    const uint4*  R  = (const uint4*)(xsb + ((size_t)bi * 4 + t) * 512); // 32

    float4 wA[8], wB[8];
    uint4 aA[2], aB[2];
#pragma unroll
    for (int u = 0; u < 8; ++u) wA[u] = w4[u];
#pragma unroll
    for (int u = 0; u < 2; ++u) aA[u] = R[u];
    float c = 0.f;
#pragma unroll
    for (int ch = 0; ch < 16; ++ch) {     // 16 chunks x 32 j
      if ((ch & 1) == 0) {
        if (ch + 1 < 16) {
          int wb0 = (ch + 1) * 8, ab0 = (ch + 1) * 2;
#pragma unroll
          for (int u = 0; u < 8; ++u) wB[u] = w4[wb0 + u];
#pragma unroll
          for (int u = 0; u < 2; ++u) aB[u] = R[ab0 + u];
        }
        consume32_u8(wA, aA, c);
      } else {
        if (ch + 1 < 16) {
          int wb0 = (ch + 1) * 8, ab0 = (ch + 1) * 2;
#pragma unroll
          for (int u = 0; u < 8; ++u) wA[u] = w4[wb0 + u];
#pragma unroll
          for (int u = 0; u < 2; ++u) aA[u] = R[ab0 + u];
        }
        consume32_u8(wB, aB, c);
      }
    }
    int lane = threadIdx.x & 63;
    int qb = lane & ~3;
    float cq[4];
    cq[0] = __shfl(c, qb + 0, 64);
    cq[1] = __shfl(c, qb + 1, 64);
    cq[2] = __shfl(c, qb + 2, 64);
    cq[3] = __shfl(c, qb + 3, 64);
    float cs = INV_STD * Gg[d];
    float cb = Bb[d], ct = Be[d];
    float m = 0.f, s = 0.f;
    u8 myb = 0;
#pragma unroll
    for (int t2 = 0; t2 < 4; ++t2) {
      float pre = (cq[t2] + cb) * cs + ct;   // identical to GEMM epilogue form
      if (t2 == 0) m = pre;
      else m = m * 0.25f * (1.0f - s) + pre;
      s = spike_of(m);
      if (t2 == t) myb = (u8)s;
    }
    S[((size_t)bi * 4 + t) * 512 + d] = myb;
  }
}

// ---------------- banded positional mixing + attn_lif (u8) ------------------
__global__ __launch_bounds__(256) void k_attn(const u8* __restrict__ qs,
    const u8* __restrict__ ks, const u8* __restrict__ vs,
    const float* __restrict__ pos_bias, u8* __restrict__ sout) {
  int idx = blockIdx.x * 256 + threadIdx.x;     // bi*128 + d4
  if (idx >= STRIDE4) return;
  const int d4 = idx & 127;
  const int bi = idx >> 7;
  const int i = bi & (L_ - 1);
  const int wmax = i < 7 ? i : 7;

  float pbv[8];
  const float* pbrow = pos_bias + (size_t)i * L_ + i;
  for (int w = 0; w <= wmax; ++w) pbv[w] = pbrow[-w];

  const uchar4* k4 = (const uchar4*)ks;
  const uchar4* v4 = (const uchar4*)vs;
  const uchar4* q4 = (const uchar4*)qs;
  float pre[T_][4];

#pragma unroll
  for (int t = 0; t < T_; ++t) {
    float sum[4] = {0.f, 0.f, 0.f, 0.f};
    for (int w = wmax; w >= 0; --w) {   // ascending j = i-w
      int rj = ((bi - w) * 4 + t) * 128 + d4;
      uchar4 ku = k4[rj];
      uchar4 vu = v4[rj];
      sum[0] += (ku.x && vu.x) ? pbv[w] : 0.0f;
      sum[1] += (ku.y && vu.y) ? pbv[w] : 0.0f;
      sum[2] += (ku.z && vu.z) ? pbv[w] : 0.0f;
      sum[3] += (ku.w && vu.w) ? pbv[w] : 0.0f;
    }
    uchar4 qu = q4[(bi * 4 + t) * 128 + d4];
    pre[t][0] = qu.x ? sum[0] : 0.0f;
    pre[t][1] = qu.y ? sum[1] : 0.0f;
    pre[t][2] = qu.z ? sum[2] : 0.0f;
    pre[t][3] = qu.w ? sum[3] : 0.0f;
  }

  uchar4* s4 = (uchar4*)sout;
  float m[4], s[4];
#pragma unroll
  for (int c = 0; c < 4; ++c) { m[c] = pre[0][c]; s[c] = spike_of(m[c]); }
  s4[(bi * 4 + 0) * 128 + d4] =
      make_uchar4((u8)s[0], (u8)s[1], (u8)s[2], (u8)s[3]);
#pragma unroll
  for (int t = 1; t < T_; ++t) {
#pragma unroll
    for (int c = 0; c < 4; ++c) {
      m[c] = m[c] * 0.25f * (1.0f - s[c]) + pre[t][c];
      s[c] = spike_of(m[c]);
    }
    s4[(bi * 4 + t) * 128 + d4] =
        make_uchar4((u8)s[0], (u8)s[1], (u8)s[2], (u8)s[3]);
  }
}

extern "C" void kernel_launch(void* const* d_in, const int* in_sizes, int n_in,
                              void* d_out, int out_size, void* d_ws, size_t ws_size,
                              hipStream_t stream) {
  (void)in_sizes; (void)n_in; (void)out_size; (void)ws_size;
  const float* x        = (const float*)d_in[0];
  const float* pos_bias = (const float*)d_in[1];
  const float* q_w    = (const float*)d_in[2];
  const float* q_b    = (const float*)d_in[3];
  const float* q_g    = (const float*)d_in[4];
  const float* q_beta = (const float*)d_in[5];
  const float* k_w    = (const float*)d_in[6];
  const float* k_b    = (const float*)d_in[7];
  const float* k_g    = (const float*)d_in[8];
  const float* k_beta = (const float*)d_in[9];
  const float* v_w    = (const float*)d_in[10];
  const float* v_b    = (const float*)d_in[11];
  const float* v_g    = (const float*)d_in[12];
  const float* v_beta = (const float*)d_in[13];
  const float* last_w    = (const float*)d_in[14];
  const float* last_b    = (const float*)d_in[15];
  const float* last_g    = (const float*)d_in[16];
  const float* last_beta = (const float*)d_in[17];
  float* out = (float*)d_out;

  char* ws = (char*)d_ws;
  u8*    xsb  = (u8*)(ws + 0);
  u8*    qs   = (u8*)(ws + 8388608);
  u8*    ks   = (u8*)(ws + 16777216);
  u8*    vs   = (u8*)(ws + 25165824);
  u8*    sA   = (u8*)(ws + 33554432);
  u8*    Wq   = (u8*)(ws + 41943040);      // 4 x 524288
  float* scl  = (float*)(ws + 46137344);   // 4 x 1024 f32
  u32*   list = (u32*)(ws + 50331648);     // 20 MB cap
  u32*   cnt  = (u32*)(ws + 73400320);

  k_wsplit<<<512, 256, 0, stream>>>(q_w, k_w, v_w, last_w, Wq, scl, cnt);
  k_lif_first<<<2048, 256, 0, stream>>>(x, xsb);

  dim3 gq(8, 64, 3);                       // colblk, rowgroup(256), mat
  k_gemm_qkv<<<gq, 256, 0, stream>>>(xsb, Wq, scl,
      q_b, q_g, q_beta, k_b, k_g, k_beta, v_b, v_g, v_beta,
      qs, ks, vs, list, cnt);

  k_fixup_c<<<2048, 128, 0, stream>>>(xsb, qs, ks, vs,
      q_w, q_b, q_g, q_beta, k_w, k_b, k_g, k_beta, v_w, v_b, v_g, v_beta,
      list, cnt);

  k_attn<<<2048, 256, 0, stream>>>(qs, ks, vs, pos_bias, sA);

  dim3 gg(8, 64);
  k_gemm_out<<<gg, 256, 0, stream>>>(sA, Wq, scl,
                                     last_b, last_g, last_beta, out);
}

// Round 9
// 323.889 us; speedup vs baseline: 1.0688x; 1.0688x over previous
//
#include <hip/hip_runtime.h>
#include <stdint.h>

// positional_spiking_attention — v9: W-resident-LDS, barrier-free i8 GEMM.
// Spikes {0,1} as u8 (exact). Weights w = s1*a1 + s2*a2 (i8 planes); i32 MFMA
// accumulation exact -> bitwise = v7/v8. Near-threshold columns (|m-0.5|<1e-3)
// compacted + recomputed with bit-exact serial fp32 chain.
// Row layout: r = bi*4 + t; lane's 4 accum regs = T=4 steps of one column.
//
// GEMM: block = 256 rows x 64 cols x 1 mat. W slab (64KB, fragment-order
// [plane][m][col][16B]) loaded to LDS ONCE (16 linear global_load_lds + one
// barrier), then a fully-unrolled ks-loop with zero barriers:
//   per ks: 4 A global dwordx4 + 8 B ds_read_b128 + 32 MFMA.
// Grid (8 colblk, 3 mat, 64 rowgroup): linear%8==colblk -> XCD pin; mats
// adjacent in dispatch order -> A rows L2-reused across q/k/v.
// Epilogue: spikes staged in 16KB LDS tile -> 64B-segment coalesced stores.
//
// Workspace:
//   0    xsb  u8 first-LIF spikes [bi*4+t][512] (8MB)
//   8M   qs / 16M ks / 24M vs / 32M sA  (u8, same layout)
//   40M  Wq   4 mats x [8 colblk][2 pl][32 m][64 c][16B] (2MB)
//   44M  scl  [mat][2][512] f32 scales
//   48M  list u32 flagged ids (cap 5M) ; 70M cnt

#define T_ 4
#define B_ 4
#define L_ 1024
#define D_ 512
#define BI_ (B_*L_)                 // 4096 (b,l) columns
#define STRIDE4 (B_*L_*D_/4)        // 524288 4-elem groups per t-slice
#define INV_STD 0.9999950000374997f
#define EPS_FLAG 1e-3f
#define LIST_CAP 5000000u

typedef unsigned int   u32;
typedef unsigned char  u8;
typedef int i32x4 __attribute__((ext_vector_type(4)));

static __device__ __forceinline__ float spike_of(float m) {
  return m > 0.5f ? 1.0f : 0.0f;
}

__device__ __forceinline__ void gll16(const void* g, void* l) {
  __builtin_amdgcn_global_load_lds(
      (const __attribute__((address_space(1))) u32*)g,
      (__attribute__((address_space(3))) u32*)l, 16, 0, 0);
}

// ------ weight quantize into fragment-ordered image (unchanged from v8) -----
__global__ __launch_bounds__(256) void k_wsplit(const float* __restrict__ qw,
    const float* __restrict__ kw, const float* __restrict__ vw,
    const float* __restrict__ lw, u8* __restrict__ Wq,
    float* __restrict__ scl, u32* __restrict__ cnt) {
  if (blockIdx.x == 0 && threadIdx.x == 0) *cnt = 0;
  int gid = blockIdx.x * 4 + (threadIdx.x >> 6);   // wave id 0..2047
  int mat = gid >> 9, e = gid & 511;
  int lane = threadIdx.x & 63;
  const float* W = mat == 0 ? qw : mat == 1 ? kw : mat == 2 ? vw : lw;
  const float4* w4 = (const float4*)(W + (size_t)e * 512 + lane * 8);
  float4 wa = w4[0], wb = w4[1];
  float w[8] = {wa.x, wa.y, wa.z, wa.w, wb.x, wb.y, wb.z, wb.w};
  float am = 0.f;
#pragma unroll
  for (int j = 0; j < 8; ++j) am = fmaxf(am, fabsf(w[j]));
#pragma unroll
  for (int off = 1; off < 64; off <<= 1)
    am = fmaxf(am, __shfl_xor(am, off, 64));
  float s1 = am > 0.f ? am * (1.0f / 127.0f) : 1.0f;
  float s2 = s1 * (1.0f / 254.0f);
  float inv1 = 1.0f / s1, inv2 = 1.0f / s2;
  u32 p1lo = 0, p1hi = 0, p2lo = 0, p2hi = 0;
#pragma unroll
  for (int j = 0; j < 8; ++j) {
    float q1 = rintf(w[j] * inv1);
    q1 = fminf(127.f, fmaxf(-127.f, q1));
    float r = w[j] - s1 * q1;
    float q2 = rintf(r * inv2);
    q2 = fminf(127.f, fmaxf(-127.f, q2));
    u32 b1 = (u32)(u8)(signed char)(int)q1;
    u32 b2 = (u32)(u8)(signed char)(int)q2;
    if (j < 4) { p1lo |= b1 << (j * 8); p2lo |= b2 << (j * 8); }
    else       { p1hi |= b1 << ((j - 4) * 8); p2hi |= b2 << ((j - 4) * 8); }
  }
  // fragment-order slab: [colblk][plane][m=j>>1... m=lane>>1][c=e&63][16B]
  u8* base = Wq + (size_t)mat * 524288 + (size_t)(e >> 6) * 65536 +
             (size_t)(lane >> 1) * 1024 + (size_t)(e & 63) * 16 + (lane & 1) * 8;
  *(uint2*)base             = make_uint2(p1lo, p1hi);   // plane 0
  *(uint2*)(base + 32768)   = make_uint2(p2lo, p2hi);   // plane 1
  if (lane == 0) {
    scl[mat * 1024 + e] = s1;
    scl[mat * 1024 + 512 + e] = s2;
  }
}

// ---------------- first LIF: x[t][bi][d] -> xsb[bi*4+t][d] (u8) -------------
__global__ __launch_bounds__(256) void k_lif_first(const float* __restrict__ x,
                                                   u8* __restrict__ xsb) {
  int idx = blockIdx.x * 256 + threadIdx.x;       // bi*128 + d4
  if (idx >= STRIDE4) return;
  const int bi = idx >> 7, d4 = idx & 127;
  const float4* x4 = (const float4*)x;
  uchar4* o4 = (uchar4*)xsb;
  float m[4], s[4];
  float4 v = x4[idx];
  m[0] = v.x; m[1] = v.y; m[2] = v.z; m[3] = v.w;
#pragma unroll
  for (int c = 0; c < 4; ++c) s[c] = spike_of(m[c]);
  o4[(bi * 4 + 0) * 128 + d4] =
      make_uchar4((u8)s[0], (u8)s[1], (u8)s[2], (u8)s[3]);
#pragma unroll
  for (int t = 1; t < T_; ++t) {
    v = x4[idx + t * STRIDE4];
    float xv[4] = {v.x, v.y, v.z, v.w};
#pragma unroll
    for (int c = 0; c < 4; ++c) {
      m[c] = m[c] * 0.25f * (1.0f - s[c]) + xv[c];
      s[c] = spike_of(m[c]);
    }
    o4[(bi * 4 + t) * 128 + d4] =
        make_uchar4((u8)s[0], (u8)s[1], (u8)s[2], (u8)s[3]);
  }
}

// ======= W-resident barrier-free i8 GEMM core ===============================
// Wave: 64 rows (4 strips of 16) x 64 cols; acc[strip][cf][plane].
// smW: 64KB fragment-order W slab already staged (caller barriered).
__device__ __forceinline__ void gemm_wres(const u8* __restrict__ Ab,
    const u8* __restrict__ smW, int rowbase, int la, int lg,
    i32x4 (&acc)[4][4][2]) {
#pragma unroll
  for (int s = 0; s < 4; ++s)
#pragma unroll
    for (int cf = 0; cf < 4; ++cf)
#pragma unroll
      for (int pl = 0; pl < 2; ++pl) acc[s][cf][pl] = (i32x4){0, 0, 0, 0};

  const u8* ap = Ab + (size_t)(rowbase + la) * 512 + lg * 16;
  const u8* bp = smW + lg * 1024 + la * 16;

#pragma unroll
  for (int ks = 0; ks < 8; ++ks) {      // fully unrolled, ZERO barriers
    uint4 Af[4];
#pragma unroll
    for (int s = 0; s < 4; ++s)
      Af[s] = *(const uint4*)(ap + s * 8192 + ks * 64);
    uint4 Bf[8];
#pragma unroll
    for (int cf = 0; cf < 4; ++cf)
#pragma unroll
      for (int pl = 0; pl < 2; ++pl)
        Bf[cf * 2 + pl] =
            *(const uint4*)(bp + pl * 32768 + ks * 4096 + cf * 256);
#pragma unroll
    for (int cf = 0; cf < 4; ++cf)
#pragma unroll
      for (int pl = 0; pl < 2; ++pl)
#pragma unroll
        for (int s = 0; s < 4; ++s)
          acc[s][cf][pl] = __builtin_amdgcn_mfma_i32_16x16x64_i8(
              __builtin_bit_cast(i32x4, Af[s]),
              __builtin_bit_cast(i32x4, Bf[cf * 2 + pl]),
              acc[s][cf][pl], 0, 0, 0);
  }
}

// ------ fused QKV: GEMM + BN + LIF epilogue, LDS-staged coalesced stores ----
__global__ __launch_bounds__(256) void k_gemm_qkv(const u8* __restrict__ Ab,
    const u8* __restrict__ Wq, const float* __restrict__ scl,
    const float* __restrict__ qb2, const float* __restrict__ qg,
    const float* __restrict__ qbe,
    const float* __restrict__ kb2, const float* __restrict__ kg,
    const float* __restrict__ kbe,
    const float* __restrict__ vb2, const float* __restrict__ vg,
    const float* __restrict__ vbe,
    u8* __restrict__ qs, u8* __restrict__ ks_, u8* __restrict__ vs,
    u32* __restrict__ list, u32* __restrict__ cnt) {
  __shared__ __align__(16) u8 smW[65536];
  __shared__ __align__(16) u8 smS[16384];      // 256 x 64 u8 spike tile
  const int tid = threadIdx.x;
  const int lane = tid & 63, wid = tid >> 6;
  const int la = lane & 15, lg = lane >> 4;
  const int colblk = blockIdx.x;               // 0..7 -> XCD pin (linear%8)
  const int tz = blockIdx.y;                   // mat
  const int row0 = blockIdx.z * 256;
  const int rowbase = row0 + wid * 64;
  const u8* Wc = Wq + (size_t)tz * 524288 + (size_t)colblk * 65536;
  const float* Bb = tz == 0 ? qb2 : tz == 1 ? kb2 : vb2;
  const float* Gg = tz == 0 ? qg  : tz == 1 ? kg  : vg;
  const float* Be = tz == 0 ? qbe : tz == 1 ? kbe : vbe;
  u8* S           = tz == 0 ? qs  : tz == 1 ? ks_ : vs;

#pragma unroll
  for (int u = 0; u < 16; ++u)
    gll16(Wc + u * 4096 + tid * 16, smW + u * 4096 + tid * 16);
  __syncthreads();                             // the ONLY pre-compute barrier

  i32x4 acc[4][4][2];
  gemm_wres(Ab, smW, rowbase, la, lg, acc);

#pragma unroll
  for (int cf = 0; cf < 4; ++cf) {
    int e = colblk * 64 + cf * 16 + la;
    float s1 = scl[tz * 1024 + e];
    float s2 = scl[tz * 1024 + 512 + e];
    float cs = INV_STD * Gg[e];
    float cb = Bb[e], ct = Be[e];
#pragma unroll
    for (int s = 0; s < 4; ++s) {
      int rl = wid * 64 + s * 16 + lg * 4;     // local row base (bi*4 aligned)
      int bi = (row0 + rl) >> 2;
      float m = 0.f, sp = 0.f;
      int fl = 0;
#pragma unroll
      for (int p = 0; p < 4; ++p) {            // p == t
        float raw = s1 * (float)acc[s][cf][0][p] + s2 * (float)acc[s][cf][1][p];
        float pre = (raw + cb) * cs + ct;
        if (p == 0) m = pre;
        else m = m * 0.25f * (1.0f - sp) + pre;
        sp = spike_of(m);
        if (fabsf(m - 0.5f) < EPS_FLAG) fl = 1;
        smS[(rl + p) * 64 + cf * 16 + la] = (u8)sp;
      }
      if (fl) {
        u32 pos = atomicAdd(cnt, 1u);
        if (pos < LIST_CAP)
          list[pos] = ((u32)tz << 21) | (u32)(bi * 512 + e);
      }
    }
  }
  __syncthreads();
  // coalesced write-out: 4 passes, 16B/lane -> 64B segments per row
#pragma unroll
  for (int ps = 0; ps < 4; ++ps) {
    int rr = ps * 64 + (tid >> 2);
    int c16 = (tid & 3) * 16;
    uint4 vv = *(const uint4*)(smS + rr * 64 + c16);
    *(uint4*)(S + (size_t)(row0 + rr) * 512 + colblk * 64 + c16) = vv;
  }
}

// -------- last GEMM + BN -> fp32 out [t][bi][d] (64B-segment stores) --------
__global__ __launch_bounds__(256) void k_gemm_out(const u8* __restrict__ Ab,
    const u8* __restrict__ Wq, const float* __restrict__ scl,
    const float* __restrict__ bias, const float* __restrict__ gamma,
    const float* __restrict__ beta, float* __restrict__ Y) {
  __shared__ __align__(16) u8 smW[65536];
  const int tid = threadIdx.x;
  const int lane = tid & 63, wid = tid >> 6;
  const int la = lane & 15, lg = lane >> 4;
  const int colblk = blockIdx.x;
  const int row0 = blockIdx.y * 256;
  const int rowbase = row0 + wid * 64;
  const u8* Wc = Wq + 3u * 524288 + (size_t)colblk * 65536;

#pragma unroll
  for (int u = 0; u < 16; ++u)
    gll16(Wc + u * 4096 + tid * 16, smW + u * 4096 + tid * 16);
  __syncthreads();

  i32x4 acc[4][4][2];
  gemm_wres(Ab, smW, rowbase, la, lg, acc);

#pragma unroll
  for (int cf = 0; cf < 4; ++cf) {
    int e = colblk * 64 + cf * 16 + la;        // 16 consecutive floats = 64B
    float s1 = scl[3 * 1024 + e];
    float s2 = scl[3 * 1024 + 512 + e];
    float cs = INV_STD * gamma[e];
    float cb = bias[e], ct = beta[e];
#pragma unroll
    for (int s = 0; s < 4; ++s) {
      int r0 = rowbase + s * 16 + lg * 4;
      int bi = r0 >> 2;
#pragma unroll
      for (int p = 0; p < 4; ++p) {
        float raw = s1 * (float)acc[s][cf][0][p] + s2 * (float)acc[s][cf][1][p];
        Y[((size_t)p * BI_ + bi) * 512 + e] = (raw + cb) * cs + ct;
      }
    }
  }
}

// ------- fixup: quad-per-item, exact serial fp32 chain, shfl-combine --------
__device__ __forceinline__ void consume32_u8(const float4 (&wb)[8],
                                             const uint4 (&ab)[2], float& c) {
#pragma unroll
  for (int u = 0; u < 8; ++u) {           // u = group of 4 consecutive j
    float4 w = wb[u];
    uint4 t = ab[u >> 2];
    u32 word = (u & 3) == 0 ? t.x : (u & 3) == 1 ? t.y
             : (u & 3) == 2 ? t.z : t.w;
    c += (word & 0xFFu)       ? w.x : 0.0f;   // strict ascending-j order
    c += (word & 0xFF00u)     ? w.y : 0.0f;
    c += (word & 0xFF0000u)   ? w.z : 0.0f;
    c += (word >> 24)         ? w.w : 0.0f;
  }
}

__global__ __launch_bounds__(128) void k_fixup_c(const u8* __restrict__ xsb,
    u8* __restrict__ qs, u8* __restrict__ ks, u8* __restrict__ vs,
    const float* __restrict__ qw, const float* __restrict__ qb2,
    const float* __restrict__ qg, const float* __restrict__ qbe,
    const float* __restrict__ kw, const float* __restrict__ kb2,
    const float* __restrict__ kg, const float* __restrict__ kbe,
    const float* __restrict__ vw, const float* __restrict__ vb2,
    const float* __restrict__ vg, const float* __restrict__ vbe,
    const u32* __restrict__ list, const u32* __restrict__ cnt) {
  u32 n = *cnt;
  if (n > LIST_CAP) n = LIST_CAP;
  u32 tot = n * 4;
  for (u32 ii = blockIdx.x * 128 + threadIdx.x; ii < tot;
       ii += gridDim.x * 128) {
    u32 i = ii >> 2;
    int t = (int)(ii & 3);
    u32 e = list[i];
    int tz = (int)(e >> 21);
    int col = (int)(e & 0x1FFFFFu);
    int bi = col >> 9, d = col & 511;
    const float* W  = tz == 0 ? qw  : tz == 1 ? kw  : vw;
    const float* Bb = tz == 0 ? qb2 : tz == 1 ? kb2 : vb2;
    const float* Gg = tz == 0 ? qg  : tz == 1 ? kg  : vg;
    const float* Be = tz == 0 ? qbe : tz == 1 ? kbe : vbe;
    u8* S           = tz == 0 ? qs  : tz == 1 ? ks  : vs;
    const float4* w4 = (const float4*)(W + (size_t)d * 512);            // 128
    const uint4*  R  = (const uint4*)(xsb + ((size_t)bi * 4 + t) * 512); // 32

    float4 wA[8], wB[8];
    uint4 aA[2], aB[2];
#pragma unroll
    for (int u = 0; u < 8; ++u) wA[u] = w4[u];
#pragma unroll
    for (int u = 0; u < 2; ++u) aA[u] = R[u];
    float c = 0.f;
#pragma unroll
    for (int ch = 0; ch < 16; ++ch) {     // 16 chunks x 32 j
      if ((ch & 1) == 0) {
        if (ch + 1 < 16) {
          int wb0 = (ch + 1) * 8, ab0 = (ch + 1) * 2;
#pragma unroll
          for (int u = 0; u < 8; ++u) wB[u] = w4[wb0 + u];
#pragma unroll
          for (int u = 0; u < 2; ++u) aB[u] = R[ab0 + u];
        }
        consume32_u8(wA, aA, c);
      } else {
        if (ch + 1 < 16) {
          int wb0 = (ch + 1) * 8, ab0 = (ch + 1) * 2;
#pragma unroll
          for (int u = 0; u < 8; ++u) wA[u] = w4[wb0 + u];
#pragma unroll
          for (int u = 0; u < 2; ++u) aA[u] = R[ab0 + u];
        }
        consume32_u8(wB, aB, c);
      }
    }
    int lane = threadIdx.x & 63;
    int qb = lane & ~3;
    float cq[4];
    cq[0] = __shfl(c, qb + 0, 64);
    cq[1] = __shfl(c, qb + 1, 64);
    cq[2] = __shfl(c, qb + 2, 64);
    cq[3] = __shfl(c, qb + 3, 64);
    float cs = INV_STD * Gg[d];
    float cb = Bb[d], ct = Be[d];
    float m = 0.f, s = 0.f;
    u8 myb = 0;
#pragma unroll
    for (int t2 = 0; t2 < 4; ++t2) {
      float pre = (cq[t2] + cb) * cs + ct;   // identical to GEMM epilogue form
      if (t2 == 0) m = pre;
      else m = m * 0.25f * (1.0f - s) + pre;
      s = spike_of(m);
      if (t2 == t) myb = (u8)s;
    }
    S[((size_t)bi * 4 + t) * 512 + d] = myb;
  }
}

// ---------------- banded positional mixing + attn_lif (u8) ------------------
__global__ __launch_bounds__(256) void k_attn(const u8* __restrict__ qs,
    const u8* __restrict__ ks, const u8* __restrict__ vs,
    const float* __restrict__ pos_bias, u8* __restrict__ sout) {
  int idx = blockIdx.x * 256 + threadIdx.x;     // bi*128 + d4
  if (idx >= STRIDE4) return;
  const int d4 = idx & 127;
  const int bi = idx >> 7;
  const int i = bi & (L_ - 1);
  const int wmax = i < 7 ? i : 7;

  float pbv[8];
  const float* pbrow = pos_bias + (size_t)i * L_ + i;
  for (int w = 0; w <= wmax; ++w) pbv[w] = pbrow[-w];

  const uchar4* k4 = (const uchar4*)ks;
  const uchar4* v4 = (const uchar4*)vs;
  const uchar4* q4 = (const uchar4*)qs;
  float pre[T_][4];

#pragma unroll
  for (int t = 0; t < T_; ++t) {
    float sum[4] = {0.f, 0.f, 0.f, 0.f};
    for (int w = wmax; w >= 0; --w) {   // ascending j = i-w
      int rj = ((bi - w) * 4 + t) * 128 + d4;
      uchar4 ku = k4[rj];
      uchar4 vu = v4[rj];
      sum[0] += (ku.x && vu.x) ? pbv[w] : 0.0f;
      sum[1] += (ku.y && vu.y) ? pbv[w] : 0.0f;
      sum[2] += (ku.z && vu.z) ? pbv[w] : 0.0f;
      sum[3] += (ku.w && vu.w) ? pbv[w] : 0.0f;
    }
    uchar4 qu = q4[(bi * 4 + t) * 128 + d4];
    pre[t][0] = qu.x ? sum[0] : 0.0f;
    pre[t][1] = qu.y ? sum[1] : 0.0f;
    pre[t][2] = qu.z ? sum[2] : 0.0f;
    pre[t][3] = qu.w ? sum[3] : 0.0f;
  }

  uchar4* s4 = (uchar4*)sout;
  float m[4], s[4];
#pragma unroll
  for (int c = 0; c < 4; ++c) { m[c] = pre[0][c]; s[c] = spike_of(m[c]); }
  s4[(bi * 4 + 0) * 128 + d4] =
      make_uchar4((u8)s[0], (u8)s[1], (u8)s[2], (u8)s[3]);
#pragma unroll
  for (int t = 1; t < T_; ++t) {
#pragma unroll
    for (int c = 0; c < 4; ++c) {
      m[c] = m[c] * 0.25f * (1.0f - s[c]) + pre[t][c];
      s[c] = spike_of(m[c]);
    }
    s4[(bi * 4 + t) * 128 + d4] =
        make_uchar4((u8)s[0], (u8)s[1], (u8)s[2], (u8)s[3]);
  }
}

extern "C" void kernel_launch(void* const* d_in, const int* in_sizes, int n_in,
                              void* d_out, int out_size, void* d_ws, size_t ws_size,
                              hipStream_t stream) {
  (void)in_sizes; (void)n_in; (void)out_size; (void)ws_size;
  const float* x        = (const float*)d_in[0];
  const float* pos_bias = (const float*)d_in[1];
  const float* q_w    = (const float*)d_in[2];
  const float* q_b    = (const float*)d_in[3];
  const float* q_g    = (const float*)d_in[4];
  const float* q_beta = (const float*)d_in[5];
  const float* k_w    = (const float*)d_in[6];
  const float* k_b    = (const float*)d_in[7];
  const float* k_g    = (const float*)d_in[8];
  const float* k_beta = (const float*)d_in[9];
  const float* v_w    = (const float*)d_in[10];
  const float* v_b    = (const float*)d_in[11];
  const float* v_g    = (const float*)d_in[12];
  const float* v_beta = (const float*)d_in[13];
  const float* last_w    = (const float*)d_in[14];
  const float* last_b    = (const float*)d_in[15];
  const float* last_g    = (const float*)d_in[16];
  const float* last_beta = (const float*)d_in[17];
  float* out = (float*)d_out;

  char* ws = (char*)d_ws;
  u8*    xsb  = (u8*)(ws + 0);
  u8*    qs   = (u8*)(ws + 8388608);
  u8*    ks   = (u8*)(ws + 16777216);
  u8*    vs   = (u8*)(ws + 25165824);
  u8*    sA   = (u8*)(ws + 33554432);
  u8*    Wq   = (u8*)(ws + 41943040);      // 4 x 524288
  float* scl  = (float*)(ws + 46137344);   // 4 x 1024 f32
  u32*   list = (u32*)(ws + 50331648);     // 20 MB cap
  u32*   cnt  = (u32*)(ws + 73400320);

  k_wsplit<<<512, 256, 0, stream>>>(q_w, k_w, v_w, last_w, Wq, scl, cnt);
  k_lif_first<<<2048, 256, 0, stream>>>(x, xsb);

  dim3 gq(8, 3, 64);                       // colblk(XCD), mat, rowgroup
  k_gemm_qkv<<<gq, 256, 0, stream>>>(xsb, Wq, scl,
      q_b, q_g, q_beta, k_b, k_g, k_beta, v_b, v_g, v_beta,
      qs, ks, vs, list, cnt);

  k_fixup_c<<<2048, 128, 0, stream>>>(xsb, qs, ks, vs,
      q_w, q_b, q_g, q_beta, k_w, k_b, k_g, k_beta, v_w, v_b, v_g, v_beta,
      list, cnt);

  k_attn<<<2048, 256, 0, stream>>>(qs, ks, vs, pos_bias, sA);

  dim3 gg(8, 64);                          // colblk, rowgroup
  k_gemm_out<<<gg, 256, 0, stream>>>(sA, Wq, scl,
                                     last_b, last_g, last_beta, out);
}